// Round 20
// baseline (223.229 us; speedup 1.0000x reference)
//
#include <hip/hip_runtime.h>
#include <math.h>

#define N_NODES 100000
#define NE 1000000
#define D_NODE 64
#define D_EDGE 32
#define HID 64
#define H2C 32
#define D_IN 160
#define NTILES (NE / 16)        // 62500
#define EPS1 1.5e-3f            // fp16-table bound (validated rounds 10-19)
#define EPS2 1e-3f              // f32-path bound (validated rounds 3-19)
#define TILES_PER_CBLOCK 245
#define LIST_CAP 400000

typedef __attribute__((ext_vector_type(8))) short short8;    // 8 bf16 or fp16
typedef __attribute__((ext_vector_type(4))) float f32x4;
typedef __attribute__((ext_vector_type(4))) float f32x4n;    // native vec for nt builtins

// ws byte layout (identical to passing v17/v19):
#define WS_A1_OFF 16
#define WS_A2_OFF (WS_A1_OFF + 8192)
#define WS_AS_OFF (WS_A2_OFF + 8192)
#define WS_AT_OFF (WS_AS_OFF + 16384)
#define WS_UHI    (WS_AT_OFF + 16384)
#define TBL_BYTES (N_NODES * HID * 2)
#define WS_ULO (WS_UHI + TBL_BYTES)
#define WS_VHI (WS_ULO + TBL_BYTES)
#define WS_VLO (WS_VHI + TBL_BYTES)
#define WS_MASK (WS_VLO + TBL_BYTES)
#define WS_LIST (WS_MASK + 125008)
#define WS_V17_MIN (WS_LIST + LIST_CAP * 4)

__device__ __forceinline__ unsigned short bf16_rne(float x) {
    unsigned int u = __float_as_uint(x);
    u += 0x7fffu + ((u >> 16) & 1u);
    return (unsigned short)(u >> 16);
}
__device__ __forceinline__ float bf16_tof(unsigned short h) {
    return __uint_as_float(((unsigned int)h) << 16);
}
__device__ __forceinline__ float h2f(unsigned short h) {
    _Float16 x = *reinterpret_cast<const _Float16*>(&h);
    return (float)x;
}
__device__ __forceinline__ unsigned short f2h(float f) {
    _Float16 x = (_Float16)f;   // RNE
    return *reinterpret_cast<const unsigned short*>(&x);
}
__device__ __forceinline__ void split8(const float* xs, short8& hi, short8& lo) {
    #pragma unroll
    for (int i = 0; i < 8; ++i) {
        unsigned short h = bf16_rne(xs[i]);
        float fh = bf16_tof(h);
        unsigned short l = bf16_rne(xs[i] - fh);
        hi[i] = (short)h;
        lo[i] = (short)l;
    }
}

// ---- Prep A (unchanged): pack a1/a2/as/at fragments; zero counters ----
__global__ void prep_pack_v15(const float* __restrict__ W1, const float* __restrict__ W2,
                              unsigned char* __restrict__ ws)
{
    const int t = blockIdx.x * blockDim.x + threadIdx.x;
    if (t == 0) { ((int*)ws)[0] = 0; ((int*)ws)[1] = 0; }
    unsigned short* a1 = (unsigned short*)(ws + WS_A1_OFF);
    unsigned short* a2 = (unsigned short*)(ws + WS_A2_OFF);
    unsigned short* as_ = (unsigned short*)(ws + WS_AS_OFF);
    unsigned short* at_ = (unsigned short*)(ws + WS_AT_OFF);
    for (int task = t; task < 1536; task += gridDim.x * blockDim.x) {
        const int l = task & 63;
        const int l15 = l & 15, kg = l >> 4;
        const float* src;
        unsigned short* dst;
        if (task < 256) {
            const int f = task >> 6;
            src = W1 + (size_t)(f*16 + l15)*D_IN + 128 + kg*8;
            dst = a1 + ((size_t)f*64 + l)*16;
        } else if (task < 512) {
            const int f = (task - 256) >> 6;
            const int nn2 = f >> 1, kk = f & 1;
            src = W2 + (size_t)(nn2*16 + l15)*HID + kk*32 + kg*8;
            dst = a2 + ((size_t)f*64 + l)*16;
        } else if (task < 1024) {
            const int f = (task - 512) >> 6;
            const int nn = f >> 1, kk = f & 1;
            src = W1 + (size_t)(nn*16 + l15)*D_IN + kk*32 + kg*8;
            dst = as_ + ((size_t)f*64 + l)*16;
        } else {
            const int f = (task - 1024) >> 6;
            const int nn = f >> 1, kk = f & 1;
            src = W1 + (size_t)(nn*16 + l15)*D_IN + 64 + kk*32 + kg*8;
            dst = at_ + ((size_t)f*64 + l)*16;
        }
        #pragma unroll
        for (int i = 0; i < 8; ++i) {
            const float wv = src[i];
            const unsigned short h = bf16_rne(wv);
            dst[i] = h;
            dst[8+i] = bf16_rne(wv - bf16_tof(h));
        }
    }
}

// ---- Prep B (unchanged): U/V tables via MFMA ----
__global__ __launch_bounds__(256) void prep_uv_v15(
    const float* __restrict__ nf, const float* __restrict__ b1,
    const unsigned short* __restrict__ asp, const unsigned short* __restrict__ atp,
    unsigned short* __restrict__ Uhi, unsigned short* __restrict__ Ulo,
    unsigned short* __restrict__ Vhi, unsigned short* __restrict__ Vlo)
{
    __shared__ __attribute__((aligned(16))) unsigned short tb[4][16 * 64];
    const int wave = threadIdx.x >> 6, lane = threadIdx.x & 63;
    const int l15 = lane & 15, kg = lane >> 4;
    const int mt = blockIdx.x * 4 + wave;
    if (mt >= N_NODES / 16) return;
    const int node0 = mt * 16;

    const float* np_ = nf + (size_t)(node0 + l15) * 64;
    short8 ahi[2], alo[2];
    #pragma unroll
    for (int kk = 0; kk < 2; ++kk) {
        const float4 x0 = *(const float4*)(np_ + kk*32 + kg*8);
        const float4 x1 = *(const float4*)(np_ + kk*32 + kg*8 + 4);
        float xs[8] = {x0.x,x0.y,x0.z,x0.w,x1.x,x1.y,x1.z,x1.w};
        split8(xs, ahi[kk], alo[kk]);
    }
    float b1v[4];
    #pragma unroll
    for (int nn = 0; nn < 4; ++nn) b1v[nn] = b1[nn*16 + l15];

    const f32x4 z4 = {0.f,0.f,0.f,0.f};
    f32x4 au[4], av[4];
    #pragma unroll
    for (int nn = 0; nn < 4; ++nn) { au[nn] = z4; av[nn] = z4; }
    #pragma unroll
    for (int kk = 0; kk < 2; ++kk) {
        #pragma unroll
        for (int nn = 0; nn < 4; ++nn) {
            const unsigned short* fs = asp + ((size_t)(nn*2+kk)*64 + lane)*16;
            const short8 bsh = *(const short8*)fs;
            const short8 bsl = *(const short8*)(fs + 8);
            au[nn] = __builtin_amdgcn_mfma_f32_16x16x32_bf16(ahi[kk], bsh, au[nn],0,0,0);
            au[nn] = __builtin_amdgcn_mfma_f32_16x16x32_bf16(ahi[kk], bsl, au[nn],0,0,0);
            au[nn] = __builtin_amdgcn_mfma_f32_16x16x32_bf16(alo[kk], bsh, au[nn],0,0,0);
            const unsigned short* ft = atp + ((size_t)(nn*2+kk)*64 + lane)*16;
            const short8 bth = *(const short8*)ft;
            const short8 btl = *(const short8*)(ft + 8);
            av[nn] = __builtin_amdgcn_mfma_f32_16x16x32_bf16(ahi[kk], bth, av[nn],0,0,0);
            av[nn] = __builtin_amdgcn_mfma_f32_16x16x32_bf16(ahi[kk], btl, av[nn],0,0,0);
            av[nn] = __builtin_amdgcn_mfma_f32_16x16x32_bf16(alo[kk], bth, av[nn],0,0,0);
        }
    }

    unsigned short uhr[4][4], ulr[4][4], vhr[4][4], vlr[4][4];
    #pragma unroll
    for (int nn = 0; nn < 4; ++nn)
        #pragma unroll
        for (int r = 0; r < 4; ++r) {
            const float u = au[nn][r] + b1v[nn];
            const unsigned short uh_ = f2h(u);
            uhr[nn][r] = uh_; ulr[nn][r] = f2h(u - h2f(uh_));
            const float v = av[nn][r];
            const unsigned short vh_ = f2h(v);
            vhr[nn][r] = vh_; vlr[nn][r] = f2h(v - h2f(vh_));
        }

    const int tnode = lane >> 2, tsl = lane & 3;
    unsigned short* const dsts[4] = {Uhi, Ulo, Vhi, Vlo};
    #pragma unroll
    for (int pass = 0; pass < 4; ++pass) {
        #pragma unroll
        for (int nn = 0; nn < 4; ++nn)
            #pragma unroll
            for (int r = 0; r < 4; ++r)
                tb[wave][(kg*4 + r)*64 + nn*16 + l15] =
                    (pass == 0) ? uhr[nn][r] :
                    (pass == 1) ? ulr[nn][r] :
                    (pass == 2) ? vhr[nn][r] : vlr[nn][r];
        asm volatile("s_waitcnt lgkmcnt(0)" ::: "memory");
        const uint4 q0 = *(const uint4*)&tb[wave][tnode*64 + tsl*16];
        const uint4 q1 = *(const uint4*)&tb[wave][tnode*64 + tsl*16 + 8];
        unsigned short* gd = dsts[pass] + (size_t)(node0 + tnode)*64 + tsl*16;
        *(uint4*)gd = q0;
        *(uint4*)(gd + 8) = q1;
        asm volatile("s_waitcnt lgkmcnt(0)" ::: "memory");
    }
}

// ---- Main v18 (unchanged from passing R19): nt streaming ----
__global__ __launch_bounds__(256) void edge_mlp_v18_kernel(
    const int* __restrict__ ei, const float* __restrict__ ef,
    const float* __restrict__ b2, const float* __restrict__ W3, const float* __restrict__ b3,
    const unsigned short* __restrict__ a1p, const unsigned short* __restrict__ a2p,
    const unsigned short* __restrict__ Uhi, const unsigned short* __restrict__ Vhi,
    unsigned short* __restrict__ maskbuf,
    float* __restrict__ out)
{
    __shared__ __attribute__((aligned(16))) float Hs[4][16][68];
    const int wave = threadIdx.x >> 6, lane = threadIdx.x & 63;
    const int l15 = lane & 15, kg = lane >> 4;
    const long long e0 = (long long)blockIdx.x * 128 + wave * 32;

    const int is64 = (ei[1]==0)&(ei[3]==0)&(ei[5]==0)&(ei[7]==0);

    int si[2], ti[2];
    const float* efpp[2];
    #pragma unroll
    for (int t = 0; t < 2; ++t) {
        long long e = e0 + t * 16 + l15;
        if (e >= NE) e = NE - 1;
        if (is64) {
            si[t] = __builtin_nontemporal_load(&ei[(size_t)(2*e)]);
            ti[t] = __builtin_nontemporal_load(&ei[(size_t)(2*(NE+e))]);
        } else {
            si[t] = __builtin_nontemporal_load(&ei[(size_t)e]);
            ti[t] = __builtin_nontemporal_load(&ei[(size_t)(NE+e)]);
        }
        efpp[t] = ef + (size_t)e * D_EDGE;
    }
    f32x4n efv[2][2];
    #pragma unroll
    for (int t = 0; t < 2; ++t) {
        efv[t][0] = __builtin_nontemporal_load((const f32x4n*)(efpp[t] + kg*8));
        efv[t][1] = __builtin_nontemporal_load((const f32x4n*)(efpp[t] + kg*8 + 4));
    }
    short8 uh[2][2], vh[2][2];
    #pragma unroll
    for (int t = 0; t < 2; ++t)
        #pragma unroll
        for (int kk = 0; kk < 2; ++kk) {
            uh[t][kk] = *(const short8*)(Uhi + (size_t)si[t]*64 + kk*32 + kg*8);
            vh[t][kk] = *(const short8*)(Vhi + (size_t)ti[t]*64 + kk*32 + kg*8);
        }

    const f32x4 z4 = {0.f,0.f,0.f,0.f};
    f32x4 acc1[2][4];
    #pragma unroll
    for (int t = 0; t < 2; ++t) {
        float xsl[8] = {efv[t][0][0],efv[t][0][1],efv[t][0][2],efv[t][0][3],
                        efv[t][1][0],efv[t][1][1],efv[t][1][2],efv[t][1][3]};
        short8 ahi, alo;
        split8(xsl, ahi, alo);
        #pragma unroll
        for (int nn = 0; nn < 4; ++nn) {
            const unsigned short* fp = a1p + ((size_t)nn*64 + lane)*16;
            const short8 bhi = *(const short8*)fp;
            const short8 blo = *(const short8*)(fp + 8);
            f32x4 a = z4;
            a = __builtin_amdgcn_mfma_f32_16x16x32_bf16(ahi, bhi, a, 0,0,0);
            a = __builtin_amdgcn_mfma_f32_16x16x32_bf16(ahi, blo, a, 0,0,0);
            a = __builtin_amdgcn_mfma_f32_16x16x32_bf16(alo, bhi, a, 0,0,0);
            acc1[t][nn] = a;
        }
    }

    const float b2a = b2[l15], b2b = b2[16 + l15];
    const float w3a = W3[l15], w3b = W3[16 + l15];
    const float b3s = b3[0];

    #pragma unroll
    for (int t = 0; t < 2; ++t) {
        #pragma unroll
        for (int nn = 0; nn < 4; ++nn)
            #pragma unroll
            for (int r = 0; r < 4; ++r)
                Hs[wave][kg*4 + r][nn*16 + l15] = acc1[t][nn][r];
        asm volatile("s_waitcnt lgkmcnt(0)" ::: "memory");

        f32x4 acc2[2] = {z4, z4};
        #pragma unroll
        for (int kk = 0; kk < 2; ++kk) {
            const float* hp = &Hs[wave][l15][kk*32 + kg*8];
            float xsl[8];
            #pragma unroll
            for (int i = 0; i < 8; ++i)
                xsl[i] = fmaxf(hp[i] + h2f((unsigned short)uh[t][kk][i])
                                     + h2f((unsigned short)vh[t][kk][i]), 0.f);
            short8 a2hi, a2lo;
            split8(xsl, a2hi, a2lo);
            #pragma unroll
            for (int nn = 0; nn < 2; ++nn) {
                const unsigned short* fp = a2p + ((size_t)(nn*2+kk)*64 + lane)*16;
                const short8 bhi = *(const short8*)fp;
                const short8 blo = *(const short8*)(fp + 8);
                acc2[nn] = __builtin_amdgcn_mfma_f32_16x16x32_bf16(a2hi, bhi, acc2[nn],0,0,0);
                acc2[nn] = __builtin_amdgcn_mfma_f32_16x16x32_bf16(a2hi, blo, acc2[nn],0,0,0);
                acc2[nn] = __builtin_amdgcn_mfma_f32_16x16x32_bf16(a2lo, bhi, acc2[nn],0,0,0);
            }
        }
        asm volatile("s_waitcnt lgkmcnt(0)" ::: "memory");

        float vv[4];
        #pragma unroll
        for (int r = 0; r < 4; ++r) {
            float x = fmaxf(acc2[0][r] + b2a, 0.f) * w3a + fmaxf(acc2[1][r] + b2b, 0.f) * w3b;
            #pragma unroll
            for (int off = 1; off < 16; off <<= 1) x += __shfl_xor(x, off, 16);
            vv[r] = x + b3s;
        }
        float lg = 0.f;
        bool valid = false;
        long long e = 0;
        if (l15 < 4) {
            lg = (l15 == 0) ? vv[0] : (l15 == 1) ? vv[1] : (l15 == 2) ? vv[2] : vv[3];
            e = e0 + t * 16 + kg * 4 + l15;
            valid = (e < NE);
            if (valid) {
                const float sc = 1.0f / (1.0f + expf(-lg));
                __builtin_nontemporal_store(sc, &out[e]);
                __builtin_nontemporal_store((sc >= 0.5f) ? 1.0f : 0.0f, &out[NE + e]);
            }
        }
        const bool flag = valid && (fabsf(lg) < EPS1);
        const unsigned long long m = __ballot(flag);
        const unsigned int mask16 = (unsigned int)( (m & 0xFull)
                                                  | ((m >> 12) & 0xF0ull)
                                                  | ((m >> 24) & 0xF00ull)
                                                  | ((m >> 36) & 0xF000ull) );
        const long long tile = (e0 + t * 16) >> 4;
        if (lane == 0 && tile < NTILES) maskbuf[tile] = (unsigned short)mask16;
    }
}

// ---- Compact (unchanged): mask1 -> dense edge list; ONE atomic per block ----
__global__ __launch_bounds__(256) void compact_v17(
    const unsigned short* __restrict__ mask1,
    int* __restrict__ counter, int* __restrict__ list)
{
    __shared__ int pref[256];
    __shared__ int sbase;
    const int tid = threadIdx.x;
    const int tile = blockIdx.x * TILES_PER_CBLOCK + tid;
    unsigned int m = 0;
    if (tid < TILES_PER_CBLOCK && tile < NTILES) m = mask1[tile];
    const int p = __popc(m);
    pref[tid] = p;
    __syncthreads();
    #pragma unroll
    for (int off = 1; off < 256; off <<= 1) {
        const int v = (tid >= off) ? pref[tid - off] : 0;
        __syncthreads();
        pref[tid] += v;
        __syncthreads();
    }
    if (tid == 255) sbase = atomicAdd(counter, pref[255]);
    __syncthreads();
    int pos = sbase + pref[tid] - p;
    unsigned int mm = m;
    while (mm) {
        const int b = __ffs(mm) - 1;
        mm &= mm - 1;
        if (pos < LIST_CAP) list[pos] = tile * 16 + b;
        ++pos;
    }
}

// ---- Fixup (unchanged body; grid restored to 2048 = R17's proven config) ----
__global__ __launch_bounds__(256) void fixup_list_v17(
    const float* __restrict__ nf, const int* __restrict__ ei,
    const float* __restrict__ ef,
    const float* __restrict__ W1, const float* __restrict__ b1,
    const float* __restrict__ W2, const float* __restrict__ b2,
    const float* __restrict__ W3, const float* __restrict__ b3,
    const unsigned short* __restrict__ Uhi, const unsigned short* __restrict__ Ulo,
    const unsigned short* __restrict__ Vhi, const unsigned short* __restrict__ Vlo,
    const int* __restrict__ counter, const int* __restrict__ list,
    float* __restrict__ out)
{
    __shared__ float W1e[64][33];
    __shared__ float W2s[32][65];
    __shared__ float fh[4][HID];
    __shared__ double dfh[4][HID];
    __shared__ __attribute__((aligned(16))) float efs[4][32];
    __shared__ __attribute__((aligned(16))) float rows[4][160];
    const int wave = threadIdx.x >> 6, lane = threadIdx.x & 63;
    int n = counter[0]; if (n > LIST_CAP) n = LIST_CAP;
    if (n == 0) return;

    for (int i = threadIdx.x; i < 64*32; i += blockDim.x)
        W1e[i >> 5][i & 31] = W1[(size_t)(i >> 5)*D_IN + 128 + (i & 31)];
    for (int i = threadIdx.x; i < 32*64; i += blockDim.x)
        W2s[i >> 6][i & 63] = W2[i];
    __syncthreads();

    const float b2l = (lane < H2C) ? b2[lane] : 0.f;
    const float w3l = (lane < H2C) ? W3[lane] : 0.f;
    const float b3s = b3[0];
    const int is64 = (ei[1]==0)&(ei[3]==0)&(ei[5]==0)&(ei[7]==0);
    const int nwaves = (gridDim.x * blockDim.x) >> 6;
    const int wid = (blockIdx.x * blockDim.x + threadIdx.x) >> 6;

    for (int i = wid; i < n; i += nwaves) {
        const int e = list[i];
        int si, ti;
        if (is64) { si = ei[(size_t)2*e]; ti = ei[(size_t)2*(NE + (long long)e)]; }
        else      { si = ei[e];           ti = ei[NE + (size_t)e]; }
        const float u = h2f(Uhi[(size_t)si*64 + lane]) + h2f(Ulo[(size_t)si*64 + lane]);
        const float v = h2f(Vhi[(size_t)ti*64 + lane]) + h2f(Vlo[(size_t)ti*64 + lane]);
        if (lane < 8)
            ((float4*)efs[wave])[lane] =
                ((const float4*)(ef + (size_t)e * D_EDGE))[lane];
        asm volatile("s_waitcnt lgkmcnt(0)" ::: "memory");
        float p0 = u + v, p1 = 0.f, p2 = 0.f, p3 = 0.f;
        #pragma unroll
        for (int k = 0; k < 32; k += 4) {
            p0 = fmaf(efs[wave][k+0], W1e[lane][k+0], p0);
            p1 = fmaf(efs[wave][k+1], W1e[lane][k+1], p1);
            p2 = fmaf(efs[wave][k+2], W1e[lane][k+2], p2);
            p3 = fmaf(efs[wave][k+3], W1e[lane][k+3], p3);
        }
        fh[wave][lane] = fmaxf((p0 + p1) + (p2 + p3), 0.f);
        asm volatile("s_waitcnt lgkmcnt(0)" ::: "memory");

        float tsum = 0.f;
        if (lane < H2C) {
            float h0 = b2l, h1 = 0.f, h2 = 0.f, h3 = 0.f;
            #pragma unroll
            for (int jj = 0; jj < 64; jj += 4) {
                h0 = fmaf(fh[wave][jj+0], W2s[lane][jj+0], h0);
                h1 = fmaf(fh[wave][jj+1], W2s[lane][jj+1], h1);
                h2 = fmaf(fh[wave][jj+2], W2s[lane][jj+2], h2);
                h3 = fmaf(fh[wave][jj+3], W2s[lane][jj+3], h3);
            }
            tsum = fmaxf((h0 + h1) + (h2 + h3), 0.f) * w3l;
        }
        #pragma unroll
        for (int off = 1; off < 32; off <<= 1) tsum += __shfl_xor(tsum, off, 32);
        int refl = 0;
        if (lane == 0) {
            const float lg = tsum + b3s;
            const float sc = 1.0f / (1.0f + expf(-lg));
            out[e] = sc;
            out[NE + (size_t)e] = (sc >= 0.5f) ? 1.0f : 0.0f;
            refl = (fabsf(lg) < EPS2) ? 1 : 0;
        }
        refl = __shfl(refl, 0, 64);
        asm volatile("s_waitcnt lgkmcnt(0)" ::: "memory");

        if (refl) {
            const float* sp = nf + (size_t)si * D_NODE;
            const float* tp = nf + (size_t)ti * D_NODE;
            const float* ep = ef + (size_t)e * D_EDGE;
            if (lane < 16)      ((float4*)&rows[wave][0])[lane]        = ((const float4*)sp)[lane];
            else if (lane < 32) ((float4*)&rows[wave][64])[lane - 16]  = ((const float4*)tp)[lane - 16];
            else if (lane < 40) ((float4*)&rows[wave][128])[lane - 32] = ((const float4*)ep)[lane - 32];
            asm volatile("s_waitcnt lgkmcnt(0)" ::: "memory");

            const float* rw = rows[wave];
            double a0 = (double)b1[lane], a1 = 0.0, a2 = 0.0, a3 = 0.0;
            const float* w1r = W1 + (size_t)lane * D_IN;
            #pragma unroll 4
            for (int k = 0; k < 160; k += 4) {
                a0 = fma((double)rw[k+0], (double)w1r[k+0], a0);
                a1 = fma((double)rw[k+1], (double)w1r[k+1], a1);
                a2 = fma((double)rw[k+2], (double)w1r[k+2], a2);
                a3 = fma((double)rw[k+3], (double)w1r[k+3], a3);
            }
            dfh[wave][lane] = fmax((a0 + a1) + (a2 + a3), 0.0);
            asm volatile("s_waitcnt lgkmcnt(0)" ::: "memory");

            double dsum = 0.0;
            if (lane < H2C) {
                double h0 = (double)b2[lane], h1 = 0.0, h2 = 0.0, h3 = 0.0;
                const float* w2r = W2 + (size_t)lane * HID;
                #pragma unroll 4
                for (int jj = 0; jj < 64; jj += 4) {
                    h0 = fma(dfh[wave][jj+0], (double)w2r[jj+0], h0);
                    h1 = fma(dfh[wave][jj+1], (double)w2r[jj+1], h1);
                    h2 = fma(dfh[wave][jj+2], (double)w2r[jj+2], h2);
                    h3 = fma(dfh[wave][jj+3], (double)w2r[jj+3], h3);
                }
                dsum = fmax((h0 + h1) + (h2 + h3), 0.0) * (double)W3[lane];
            }
            #pragma unroll
            for (int off = 1; off < 32; off <<= 1) dsum += __shfl_xor(dsum, off, 32);
            if (lane == 0) {
                const double logit = dsum + (double)b3[0];
                const float sc = (float)(1.0 / (1.0 + exp(-logit)));
                out[e] = sc;
                out[NE + (size_t)e] = (sc >= 0.5f) ? 1.0f : 0.0f;
            }
            asm volatile("s_waitcnt lgkmcnt(0)" ::: "memory");
        }
    }
}

// ---------- Fallback (tiny ws): proven f32 VALU path + atomic list ----------
__global__ void zero_counter_kernel(int* __restrict__ c) {
    if (blockIdx.x == 0 && threadIdx.x == 0) c[0] = 0;
}

__global__ __launch_bounds__(256, 4) void edge_mlp_f32_kernel(
    const float* __restrict__ nf, const int* __restrict__ ei,
    const float* __restrict__ ef,
    const float* __restrict__ W1, const float* __restrict__ b1,
    const float* __restrict__ W2, const float* __restrict__ b2,
    const float* __restrict__ W3, const float* __restrict__ b3,
    int* __restrict__ counter, int* __restrict__ list, int cap,
    float* __restrict__ out)
{
    const int e = blockIdx.x * blockDim.x + threadIdx.x;
    if (e >= NE) return;
    const int is64 = (ei[1]==0)&(ei[3]==0)&(ei[5]==0)&(ei[7]==0);
    int si, ti;
    if (is64) { si = ei[2*(size_t)e]; ti = ei[2*((size_t)NE + e)]; }
    else      { si = ei[e];           ti = ei[NE + e]; }
    const float* srcp = nf + (size_t)si * D_NODE;
    const float* tgtp = nf + (size_t)ti * D_NODE;
    const float* efp  = ef + (size_t)e  * D_EDGE;

    float acc[HID];
    #pragma unroll
    for (int j = 0; j < HID; ++j) acc[j] = b1[j];
    #pragma unroll 1
    for (int kc = 0; kc < D_IN / 16; ++kc) {
        const float* base = (kc < 4) ? (srcp + kc * 16)
                          : (kc < 8) ? (tgtp + (kc - 4) * 16)
                                     : (efp  + (kc - 8) * 16);
        float c[16];
        #pragma unroll
        for (int q = 0; q < 4; ++q) {
            const float4 v = *reinterpret_cast<const float4*>(base + q * 4);
            c[q*4+0]=v.x; c[q*4+1]=v.y; c[q*4+2]=v.z; c[q*4+3]=v.w;
        }
        #pragma unroll
        for (int j = 0; j < HID; ++j)
            #pragma unroll
            for (int q = 0; q < 16; ++q)
                acc[j] = fmaf(c[q], W1[j*D_IN + kc*16 + q], acc[j]);
    }
    #pragma unroll
    for (int j = 0; j < HID; ++j) acc[j] = fmaxf(acc[j], 0.0f);

    float logit = b3[0];
    #pragma unroll 1
    for (int jj = 0; jj < H2C; ++jj) {
        float h = b2[jj];
        #pragma unroll
        for (int j = 0; j < HID; ++j) h = fmaf(acc[j], W2[jj*HID + j], h);
        logit = fmaf(fmaxf(h, 0.0f), W3[jj], logit);
    }
    const float score = 1.0f / (1.0f + expf(-logit));
    out[e] = score;
    out[(size_t)NE + e] = (score >= 0.5f) ? 1.0f : 0.0f;
    if (fabsf(logit) < EPS2) {
        const int idx = atomicAdd(counter, 1);
        if (idx < cap) list[idx] = e;
    }
}

__global__ __launch_bounds__(256) void fixup_list_f64_kernel(
    const float* __restrict__ nf, const int* __restrict__ ei,
    const float* __restrict__ ef,
    const float* __restrict__ W1, const float* __restrict__ b1,
    const float* __restrict__ W2, const float* __restrict__ b2,
    const float* __restrict__ W3, const float* __restrict__ b3,
    const int* __restrict__ counter, const int* __restrict__ list, int cap,
    float* __restrict__ out)
{
    __shared__ double fh[4][HID];
    __shared__ __attribute__((aligned(16))) float rows[4][160];
    const int wave = threadIdx.x >> 6, lane = threadIdx.x & 63;
    const int nwaves = (gridDim.x * blockDim.x) >> 6;
    const int wid = (blockIdx.x * blockDim.x + threadIdx.x) >> 6;
    int n = counter[0]; if (n > cap) n = cap;
    const int is64 = (ei[1]==0)&(ei[3]==0)&(ei[5]==0)&(ei[7]==0);

    for (int i = wid; i < n; i += nwaves) {
        const int e = list[i];
        int si, ti;
        if (is64) { si = ei[(size_t)2*e]; ti = ei[(size_t)2*(NE + (long long)e)]; }
        else      { si = ei[e];           ti = ei[NE + (size_t)e]; }
        const float* sp = nf + (size_t)si * D_NODE;
        const float* tp = nf + (size_t)ti * D_NODE;
        const float* ep = ef + (size_t)e * D_EDGE;

        if (lane < 16)      ((float4*)&rows[wave][0])[lane]        = ((const float4*)sp)[lane];
        else if (lane < 32) ((float4*)&rows[wave][64])[lane - 16]  = ((const float4*)tp)[lane - 16];
        else if (lane < 40) ((float4*)&rows[wave][128])[lane - 32] = ((const float4*)ep)[lane - 32];
        asm volatile("s_waitcnt lgkmcnt(0)" ::: "memory");

        const float* rw = rows[wave];
        double a0 = (double)b1[lane], a1 = 0.0, a2 = 0.0, a3 = 0.0;
        const float* w1r = W1 + (size_t)lane * D_IN;
        #pragma unroll 4
        for (int k = 0; k < 160; k += 4) {
            a0 = fma((double)rw[k+0], (double)w1r[k+0], a0);
            a1 = fma((double)rw[k+1], (double)w1r[k+1], a1);
            a2 = fma((double)rw[k+2], (double)w1r[k+2], a2);
            a3 = fma((double)rw[k+3], (double)w1r[k+3], a3);
        }
        fh[wave][lane] = fmax((a0 + a1) + (a2 + a3), 0.0);
        asm volatile("s_waitcnt lgkmcnt(0)" ::: "memory");

        double tsum = 0.0;
        if (lane < H2C) {
            double h0 = (double)b2[lane], h1 = 0.0, h2 = 0.0, h3 = 0.0;
            const float* w2r = W2 + (size_t)lane * HID;
            #pragma unroll 4
            for (int jj = 0; jj < 64; jj += 4) {
                h0 = fma(fh[wave][jj+0], (double)w2r[jj+0], h0);
                h1 = fma(fh[wave][jj+1], (double)w2r[jj+1], h1);
                h2 = fma(fh[wave][jj+2], (double)w2r[jj+2], h2);
                h3 = fma(fh[wave][jj+3], (double)w2r[jj+3], h3);
            }
            tsum = fmax((h0 + h1) + (h2 + h3), 0.0) * (double)W3[lane];
        }
        #pragma unroll
        for (int off = 1; off < 32; off <<= 1) tsum += __shfl_xor(tsum, off, 32);
        if (lane == 0) {
            const double logit = tsum + (double)b3[0];
            const float sc = (float)(1.0 / (1.0 + exp(-logit)));
            out[e] = sc;
            out[NE + (size_t)e] = (sc >= 0.5f) ? 1.0f : 0.0f;
        }
        asm volatile("s_waitcnt lgkmcnt(0)" ::: "memory");
    }
}

extern "C" void kernel_launch(void* const* d_in, const int* in_sizes, int n_in,
                              void* d_out, int out_size, void* d_ws, size_t ws_size,
                              hipStream_t stream) {
    const float* nf = (const float*)d_in[0];
    const int*   ei = (const int*)  d_in[1];
    const float* ef = (const float*)d_in[2];
    const float* W1 = (const float*)d_in[3];
    const float* b1 = (const float*)d_in[4];
    const float* W2 = (const float*)d_in[5];
    const float* b2 = (const float*)d_in[6];
    const float* W3 = (const float*)d_in[7];
    const float* b3 = (const float*)d_in[8];
    float* out = (float*)d_out;
    unsigned char* ws = (unsigned char*)d_ws;

    if (ws_size >= (size_t)WS_V17_MIN) {
        unsigned short* Uhi = (unsigned short*)(ws + WS_UHI);
        unsigned short* Ulo = (unsigned short*)(ws + WS_ULO);
        unsigned short* Vhi = (unsigned short*)(ws + WS_VHI);
        unsigned short* Vlo = (unsigned short*)(ws + WS_VLO);
        unsigned short* mask1 = (unsigned short*)(ws + WS_MASK);
        int* counter = (int*)ws;
        int* list = (int*)(ws + WS_LIST);
        hipLaunchKernelGGL(prep_pack_v15, dim3(6), dim3(256), 0, stream, W1, W2, ws);
        hipLaunchKernelGGL(prep_uv_v15, dim3((N_NODES/16 + 3) / 4), dim3(256), 0, stream,
                           nf, b1,
                           (const unsigned short*)(ws + WS_AS_OFF),
                           (const unsigned short*)(ws + WS_AT_OFF),
                           Uhi, Ulo, Vhi, Vlo);
        hipLaunchKernelGGL(edge_mlp_v18_kernel, dim3((NE + 127) / 128), dim3(256), 0, stream,
                           ei, ef, b2, W3, b3,
                           (const unsigned short*)(ws + WS_A1_OFF),
                           (const unsigned short*)(ws + WS_A2_OFF),
                           Uhi, Vhi, mask1, out);
        hipLaunchKernelGGL(compact_v17, dim3(256), dim3(256), 0, stream,
                           mask1, counter, list);
        hipLaunchKernelGGL(fixup_list_v17, dim3(2048), dim3(256), 0, stream,
                           nf, ei, ef, W1, b1, W2, b2, W3, b3,
                           Uhi, Ulo, Vhi, Vlo, counter, list, out);
    } else {
        int* counter = (int*)ws;
        long long cap_ll = ((long long)ws_size - 16) / 4;
        const int cap = (int)(cap_ll < 0 ? 0 : (cap_ll > NE ? NE : cap_ll));
        int* slist = (int*)(ws + 16);
        hipLaunchKernelGGL(zero_counter_kernel, dim3(1), dim3(64), 0, stream, counter);
        hipLaunchKernelGGL(edge_mlp_f32_kernel, dim3((NE + 255)/256), dim3(256), 0, stream,
                           nf, ei, ef, W1, b1, W2, b2, W3, b3, counter, slist, cap, out);
        hipLaunchKernelGGL(fixup_list_f64_kernel, dim3(512), dim3(256), 0, stream,
                           nf, ei, ef, W1, b1, W2, b2, W3, b3, counter, slist, cap, out);
    }
}

// Round 21
// 212.853 us; speedup vs baseline: 1.0488x; 1.0488x over previous
//
#include <hip/hip_runtime.h>
#include <math.h>

#define N_NODES 100000
#define NE 1000000
#define D_NODE 64
#define D_EDGE 32
#define HID 64
#define H2C 32
#define D_IN 160
#define NTILES (NE / 16)        // 62500
#define EPS1 1.5e-3f            // fp16-table bound (validated rounds 10-20)
#define EPS2 1e-3f              // f32-path bound (validated rounds 3-20)
#define TILES_PER_CBLOCK 245
#define LIST_CAP 400000

typedef __attribute__((ext_vector_type(8))) short short8;   // 8 bf16 or fp16
typedef __attribute__((ext_vector_type(4))) float f32x4;

// ws byte layout (identical to passing v17):
#define WS_A1_OFF 16
#define WS_A2_OFF (WS_A1_OFF + 8192)
#define WS_AS_OFF (WS_A2_OFF + 8192)
#define WS_AT_OFF (WS_AS_OFF + 16384)
#define WS_UHI    (WS_AT_OFF + 16384)
#define TBL_BYTES (N_NODES * HID * 2)
#define WS_ULO (WS_UHI + TBL_BYTES)
#define WS_VHI (WS_ULO + TBL_BYTES)
#define WS_VLO (WS_VHI + TBL_BYTES)
#define WS_MASK (WS_VLO + TBL_BYTES)
#define WS_LIST (WS_MASK + 125008)
#define WS_V17_MIN (WS_LIST + LIST_CAP * 4)

__device__ __forceinline__ unsigned short bf16_rne(float x) {
    unsigned int u = __float_as_uint(x);
    u += 0x7fffu + ((u >> 16) & 1u);
    return (unsigned short)(u >> 16);
}
__device__ __forceinline__ float bf16_tof(unsigned short h) {
    return __uint_as_float(((unsigned int)h) << 16);
}
__device__ __forceinline__ float h2f(unsigned short h) {
    _Float16 x = *reinterpret_cast<const _Float16*>(&h);
    return (float)x;
}
__device__ __forceinline__ unsigned short f2h(float f) {
    _Float16 x = (_Float16)f;   // RNE
    return *reinterpret_cast<const unsigned short*>(&x);
}
__device__ __forceinline__ void split8(const float* xs, short8& hi, short8& lo) {
    #pragma unroll
    for (int i = 0; i < 8; ++i) {
        unsigned short h = bf16_rne(xs[i]);
        float fh = bf16_tof(h);
        unsigned short l = bf16_rne(xs[i] - fh);
        hi[i] = (short)h;
        lo[i] = (short)l;
    }
}

// ---- Prep A: pack a1/a2/as/at fragments; zero counters ----
__global__ void prep_pack_v15(const float* __restrict__ W1, const float* __restrict__ W2,
                              unsigned char* __restrict__ ws)
{
    const int t = blockIdx.x * blockDim.x + threadIdx.x;
    if (t == 0) { ((int*)ws)[0] = 0; ((int*)ws)[1] = 0; }
    unsigned short* a1 = (unsigned short*)(ws + WS_A1_OFF);
    unsigned short* a2 = (unsigned short*)(ws + WS_A2_OFF);
    unsigned short* as_ = (unsigned short*)(ws + WS_AS_OFF);
    unsigned short* at_ = (unsigned short*)(ws + WS_AT_OFF);
    for (int task = t; task < 1536; task += gridDim.x * blockDim.x) {
        const int l = task & 63;
        const int l15 = l & 15, kg = l >> 4;
        const float* src;
        unsigned short* dst;
        if (task < 256) {
            const int f = task >> 6;
            src = W1 + (size_t)(f*16 + l15)*D_IN + 128 + kg*8;
            dst = a1 + ((size_t)f*64 + l)*16;
        } else if (task < 512) {
            const int f = (task - 256) >> 6;
            const int nn2 = f >> 1, kk = f & 1;
            src = W2 + (size_t)(nn2*16 + l15)*HID + kk*32 + kg*8;
            dst = a2 + ((size_t)f*64 + l)*16;
        } else if (task < 1024) {
            const int f = (task - 512) >> 6;
            const int nn = f >> 1, kk = f & 1;
            src = W1 + (size_t)(nn*16 + l15)*D_IN + kk*32 + kg*8;
            dst = as_ + ((size_t)f*64 + l)*16;
        } else {
            const int f = (task - 1024) >> 6;
            const int nn = f >> 1, kk = f & 1;
            src = W1 + (size_t)(nn*16 + l15)*D_IN + 64 + kk*32 + kg*8;
            dst = at_ + ((size_t)f*64 + l)*16;
        }
        #pragma unroll
        for (int i = 0; i < 8; ++i) {
            const float wv = src[i];
            const unsigned short h = bf16_rne(wv);
            dst[i] = h;
            dst[8+i] = bf16_rne(wv - bf16_tof(h));
        }
    }
}

// ---- Prep B: U/V tables via MFMA ----
__global__ __launch_bounds__(256) void prep_uv_v15(
    const float* __restrict__ nf, const float* __restrict__ b1,
    const unsigned short* __restrict__ asp, const unsigned short* __restrict__ atp,
    unsigned short* __restrict__ Uhi, unsigned short* __restrict__ Ulo,
    unsigned short* __restrict__ Vhi, unsigned short* __restrict__ Vlo)
{
    __shared__ __attribute__((aligned(16))) unsigned short tb[4][16 * 64];
    const int wave = threadIdx.x >> 6, lane = threadIdx.x & 63;
    const int l15 = lane & 15, kg = lane >> 4;
    const int mt = blockIdx.x * 4 + wave;
    if (mt >= N_NODES / 16) return;
    const int node0 = mt * 16;

    const float* np_ = nf + (size_t)(node0 + l15) * 64;
    short8 ahi[2], alo[2];
    #pragma unroll
    for (int kk = 0; kk < 2; ++kk) {
        const float4 x0 = *(const float4*)(np_ + kk*32 + kg*8);
        const float4 x1 = *(const float4*)(np_ + kk*32 + kg*8 + 4);
        float xs[8] = {x0.x,x0.y,x0.z,x0.w,x1.x,x1.y,x1.z,x1.w};
        split8(xs, ahi[kk], alo[kk]);
    }
    float b1v[4];
    #pragma unroll
    for (int nn = 0; nn < 4; ++nn) b1v[nn] = b1[nn*16 + l15];

    const f32x4 z4 = {0.f,0.f,0.f,0.f};
    f32x4 au[4], av[4];
    #pragma unroll
    for (int nn = 0; nn < 4; ++nn) { au[nn] = z4; av[nn] = z4; }
    #pragma unroll
    for (int kk = 0; kk < 2; ++kk) {
        #pragma unroll
        for (int nn = 0; nn < 4; ++nn) {
            const unsigned short* fs = asp + ((size_t)(nn*2+kk)*64 + lane)*16;
            const short8 bsh = *(const short8*)fs;
            const short8 bsl = *(const short8*)(fs + 8);
            au[nn] = __builtin_amdgcn_mfma_f32_16x16x32_bf16(ahi[kk], bsh, au[nn],0,0,0);
            au[nn] = __builtin_amdgcn_mfma_f32_16x16x32_bf16(ahi[kk], bsl, au[nn],0,0,0);
            au[nn] = __builtin_amdgcn_mfma_f32_16x16x32_bf16(alo[kk], bsh, au[nn],0,0,0);
            const unsigned short* ft = atp + ((size_t)(nn*2+kk)*64 + lane)*16;
            const short8 bth = *(const short8*)ft;
            const short8 btl = *(const short8*)(ft + 8);
            av[nn] = __builtin_amdgcn_mfma_f32_16x16x32_bf16(ahi[kk], bth, av[nn],0,0,0);
            av[nn] = __builtin_amdgcn_mfma_f32_16x16x32_bf16(ahi[kk], btl, av[nn],0,0,0);
            av[nn] = __builtin_amdgcn_mfma_f32_16x16x32_bf16(alo[kk], bth, av[nn],0,0,0);
        }
    }

    unsigned short uhr[4][4], ulr[4][4], vhr[4][4], vlr[4][4];
    #pragma unroll
    for (int nn = 0; nn < 4; ++nn)
        #pragma unroll
        for (int r = 0; r < 4; ++r) {
            const float u = au[nn][r] + b1v[nn];
            const unsigned short uh_ = f2h(u);
            uhr[nn][r] = uh_; ulr[nn][r] = f2h(u - h2f(uh_));
            const float v = av[nn][r];
            const unsigned short vh_ = f2h(v);
            vhr[nn][r] = vh_; vlr[nn][r] = f2h(v - h2f(vh_));
        }

    const int tnode = lane >> 2, tsl = lane & 3;
    unsigned short* const dsts[4] = {Uhi, Ulo, Vhi, Vlo};
    #pragma unroll
    for (int pass = 0; pass < 4; ++pass) {
        #pragma unroll
        for (int nn = 0; nn < 4; ++nn)
            #pragma unroll
            for (int r = 0; r < 4; ++r)
                tb[wave][(kg*4 + r)*64 + nn*16 + l15] =
                    (pass == 0) ? uhr[nn][r] :
                    (pass == 1) ? ulr[nn][r] :
                    (pass == 2) ? vhr[nn][r] : vlr[nn][r];
        asm volatile("s_waitcnt lgkmcnt(0)" ::: "memory");
        const uint4 q0 = *(const uint4*)&tb[wave][tnode*64 + tsl*16];
        const uint4 q1 = *(const uint4*)&tb[wave][tnode*64 + tsl*16 + 8];
        unsigned short* gd = dsts[pass] + (size_t)(node0 + tnode)*64 + tsl*16;
        *(uint4*)gd = q0;
        *(uint4*)(gd + 8) = q1;
        asm volatile("s_waitcnt lgkmcnt(0)" ::: "memory");
    }
}

// ---- Main v8 (R17's proven main; no nt) ----
__global__ __launch_bounds__(256) void edge_mlp_v8_kernel(
    const int* __restrict__ ei, const float* __restrict__ ef,
    const float* __restrict__ b2, const float* __restrict__ W3, const float* __restrict__ b3,
    const unsigned short* __restrict__ a1p, const unsigned short* __restrict__ a2p,
    const unsigned short* __restrict__ Uhi, const unsigned short* __restrict__ Vhi,
    unsigned short* __restrict__ maskbuf,
    float* __restrict__ out)
{
    __shared__ __attribute__((aligned(16))) float Hs[4][16][68];
    const int wave = threadIdx.x >> 6, lane = threadIdx.x & 63;
    const int l15 = lane & 15, kg = lane >> 4;
    const long long e0 = (long long)blockIdx.x * 128 + wave * 32;

    const int is64 = (ei[1]==0)&(ei[3]==0)&(ei[5]==0)&(ei[7]==0);

    int si[2], ti[2];
    const float* efpp[2];
    #pragma unroll
    for (int t = 0; t < 2; ++t) {
        long long e = e0 + t * 16 + l15;
        if (e >= NE) e = NE - 1;
        if (is64) { si[t] = ei[(size_t)(2*e)]; ti[t] = ei[(size_t)(2*(NE+e))]; }
        else      { si[t] = ei[(size_t)e];     ti[t] = ei[(size_t)(NE+e)]; }
        efpp[t] = ef + (size_t)e * D_EDGE;
    }
    float4 efv[2][2];
    #pragma unroll
    for (int t = 0; t < 2; ++t) {
        efv[t][0] = *(const float4*)(efpp[t] + kg*8);
        efv[t][1] = *(const float4*)(efpp[t] + kg*8 + 4);
    }
    short8 uh[2][2], vh[2][2];
    #pragma unroll
    for (int t = 0; t < 2; ++t)
        #pragma unroll
        for (int kk = 0; kk < 2; ++kk) {
            uh[t][kk] = *(const short8*)(Uhi + (size_t)si[t]*64 + kk*32 + kg*8);
            vh[t][kk] = *(const short8*)(Vhi + (size_t)ti[t]*64 + kk*32 + kg*8);
        }

    const f32x4 z4 = {0.f,0.f,0.f,0.f};
    f32x4 acc1[2][4];
    #pragma unroll
    for (int t = 0; t < 2; ++t) {
        float xsl[8] = {efv[t][0].x,efv[t][0].y,efv[t][0].z,efv[t][0].w,
                        efv[t][1].x,efv[t][1].y,efv[t][1].z,efv[t][1].w};
        short8 ahi, alo;
        split8(xsl, ahi, alo);
        #pragma unroll
        for (int nn = 0; nn < 4; ++nn) {
            const unsigned short* fp = a1p + ((size_t)nn*64 + lane)*16;
            const short8 bhi = *(const short8*)fp;
            const short8 blo = *(const short8*)(fp + 8);
            f32x4 a = z4;
            a = __builtin_amdgcn_mfma_f32_16x16x32_bf16(ahi, bhi, a, 0,0,0);
            a = __builtin_amdgcn_mfma_f32_16x16x32_bf16(ahi, blo, a, 0,0,0);
            a = __builtin_amdgcn_mfma_f32_16x16x32_bf16(alo, bhi, a, 0,0,0);
            acc1[t][nn] = a;
        }
    }

    const float b2a = b2[l15], b2b = b2[16 + l15];
    const float w3a = W3[l15], w3b = W3[16 + l15];
    const float b3s = b3[0];

    #pragma unroll
    for (int t = 0; t < 2; ++t) {
        #pragma unroll
        for (int nn = 0; nn < 4; ++nn)
            #pragma unroll
            for (int r = 0; r < 4; ++r)
                Hs[wave][kg*4 + r][nn*16 + l15] = acc1[t][nn][r];
        asm volatile("s_waitcnt lgkmcnt(0)" ::: "memory");

        f32x4 acc2[2] = {z4, z4};
        #pragma unroll
        for (int kk = 0; kk < 2; ++kk) {
            const float* hp = &Hs[wave][l15][kk*32 + kg*8];
            float xsl[8];
            #pragma unroll
            for (int i = 0; i < 8; ++i)
                xsl[i] = fmaxf(hp[i] + h2f((unsigned short)uh[t][kk][i])
                                     + h2f((unsigned short)vh[t][kk][i]), 0.f);
            short8 a2hi, a2lo;
            split8(xsl, a2hi, a2lo);
            #pragma unroll
            for (int nn = 0; nn < 2; ++nn) {
                const unsigned short* fp = a2p + ((size_t)(nn*2+kk)*64 + lane)*16;
                const short8 bhi = *(const short8*)fp;
                const short8 blo = *(const short8*)(fp + 8);
                acc2[nn] = __builtin_amdgcn_mfma_f32_16x16x32_bf16(a2hi, bhi, acc2[nn],0,0,0);
                acc2[nn] = __builtin_amdgcn_mfma_f32_16x16x32_bf16(a2hi, blo, acc2[nn],0,0,0);
                acc2[nn] = __builtin_amdgcn_mfma_f32_16x16x32_bf16(a2lo, bhi, acc2[nn],0,0,0);
            }
        }
        asm volatile("s_waitcnt lgkmcnt(0)" ::: "memory");

        float vv[4];
        #pragma unroll
        for (int r = 0; r < 4; ++r) {
            float x = fmaxf(acc2[0][r] + b2a, 0.f) * w3a + fmaxf(acc2[1][r] + b2b, 0.f) * w3b;
            #pragma unroll
            for (int off = 1; off < 16; off <<= 1) x += __shfl_xor(x, off, 16);
            vv[r] = x + b3s;
        }
        float lg = 0.f;
        bool valid = false;
        long long e = 0;
        if (l15 < 4) {
            lg = (l15 == 0) ? vv[0] : (l15 == 1) ? vv[1] : (l15 == 2) ? vv[2] : vv[3];
            e = e0 + t * 16 + kg * 4 + l15;
            valid = (e < NE);
            if (valid) {
                const float sc = 1.0f / (1.0f + expf(-lg));
                out[e] = sc;
                out[NE + e] = (sc >= 0.5f) ? 1.0f : 0.0f;
            }
        }
        const bool flag = valid && (fabsf(lg) < EPS1);
        const unsigned long long m = __ballot(flag);
        const unsigned int mask16 = (unsigned int)( (m & 0xFull)
                                                  | ((m >> 12) & 0xF0ull)
                                                  | ((m >> 24) & 0xF00ull)
                                                  | ((m >> 36) & 0xF000ull) );
        const long long tile = (e0 + t * 16) >> 4;
        if (lane == 0 && tile < NTILES) maskbuf[tile] = (unsigned short)mask16;
    }
}

// ---- Compact: mask1 -> dense edge list; ONE atomic per block ----
__global__ __launch_bounds__(256) void compact_v17(
    const unsigned short* __restrict__ mask1,
    int* __restrict__ counter, int* __restrict__ list)
{
    __shared__ int pref[256];
    __shared__ int sbase;
    const int tid = threadIdx.x;
    const int tile = blockIdx.x * TILES_PER_CBLOCK + tid;
    unsigned int m = 0;
    if (tid < TILES_PER_CBLOCK && tile < NTILES) m = mask1[tile];
    const int p = __popc(m);
    pref[tid] = p;
    __syncthreads();
    #pragma unroll
    for (int off = 1; off < 256; off <<= 1) {
        const int v = (tid >= off) ? pref[tid - off] : 0;
        __syncthreads();
        pref[tid] += v;
        __syncthreads();
    }
    if (tid == 255) sbase = atomicAdd(counter, pref[255]);
    __syncthreads();
    int pos = sbase + pref[tid] - p;
    unsigned int mm = m;
    while (mm) {
        const int b = __ffs(mm) - 1;
        mm &= mm - 1;
        if (pos < LIST_CAP) list[pos] = tile * 16 + b;
        ++pos;
    }
}

// ---- Fixup: wave-per-edge over the dense list (grid 2048) ----
__global__ __launch_bounds__(256) void fixup_list_v17(
    const float* __restrict__ nf, const int* __restrict__ ei,
    const float* __restrict__ ef,
    const float* __restrict__ W1, const float* __restrict__ b1,
    const float* __restrict__ W2, const float* __restrict__ b2,
    const float* __restrict__ W3, const float* __restrict__ b3,
    const unsigned short* __restrict__ Uhi, const unsigned short* __restrict__ Ulo,
    const unsigned short* __restrict__ Vhi, const unsigned short* __restrict__ Vlo,
    const int* __restrict__ counter, const int* __restrict__ list,
    float* __restrict__ out)
{
    __shared__ float W1e[64][33];
    __shared__ float W2s[32][65];
    __shared__ float fh[4][HID];
    __shared__ double dfh[4][HID];
    __shared__ __attribute__((aligned(16))) float efs[4][32];
    __shared__ __attribute__((aligned(16))) float rows[4][160];
    const int wave = threadIdx.x >> 6, lane = threadIdx.x & 63;
    int n = counter[0]; if (n > LIST_CAP) n = LIST_CAP;
    if (n == 0) return;

    for (int i = threadIdx.x; i < 64*32; i += blockDim.x)
        W1e[i >> 5][i & 31] = W1[(size_t)(i >> 5)*D_IN + 128 + (i & 31)];
    for (int i = threadIdx.x; i < 32*64; i += blockDim.x)
        W2s[i >> 6][i & 63] = W2[i];
    __syncthreads();

    const float b2l = (lane < H2C) ? b2[lane] : 0.f;
    const float w3l = (lane < H2C) ? W3[lane] : 0.f;
    const float b3s = b3[0];
    const int is64 = (ei[1]==0)&(ei[3]==0)&(ei[5]==0)&(ei[7]==0);
    const int nwaves = (gridDim.x * blockDim.x) >> 6;
    const int wid = (blockIdx.x * blockDim.x + threadIdx.x) >> 6;

    for (int i = wid; i < n; i += nwaves) {
        const int e = list[i];
        int si, ti;
        if (is64) { si = ei[(size_t)2*e]; ti = ei[(size_t)2*(NE + (long long)e)]; }
        else      { si = ei[e];           ti = ei[NE + (size_t)e]; }
        const float u = h2f(Uhi[(size_t)si*64 + lane]) + h2f(Ulo[(size_t)si*64 + lane]);
        const float v = h2f(Vhi[(size_t)ti*64 + lane]) + h2f(Vlo[(size_t)ti*64 + lane]);
        if (lane < 8)
            ((float4*)efs[wave])[lane] =
                ((const float4*)(ef + (size_t)e * D_EDGE))[lane];
        asm volatile("s_waitcnt lgkmcnt(0)" ::: "memory");
        float p0 = u + v, p1 = 0.f, p2 = 0.f, p3 = 0.f;
        #pragma unroll
        for (int k = 0; k < 32; k += 4) {
            p0 = fmaf(efs[wave][k+0], W1e[lane][k+0], p0);
            p1 = fmaf(efs[wave][k+1], W1e[lane][k+1], p1);
            p2 = fmaf(efs[wave][k+2], W1e[lane][k+2], p2);
            p3 = fmaf(efs[wave][k+3], W1e[lane][k+3], p3);
        }
        fh[wave][lane] = fmaxf((p0 + p1) + (p2 + p3), 0.f);
        asm volatile("s_waitcnt lgkmcnt(0)" ::: "memory");

        float tsum = 0.f;
        if (lane < H2C) {
            float h0 = b2l, h1 = 0.f, h2 = 0.f, h3 = 0.f;
            #pragma unroll
            for (int jj = 0; jj < 64; jj += 4) {
                h0 = fmaf(fh[wave][jj+0], W2s[lane][jj+0], h0);
                h1 = fmaf(fh[wave][jj+1], W2s[lane][jj+1], h1);
                h2 = fmaf(fh[wave][jj+2], W2s[lane][jj+2], h2);
                h3 = fmaf(fh[wave][jj+3], W2s[lane][jj+3], h3);
            }
            tsum = fmaxf((h0 + h1) + (h2 + h3), 0.f) * w3l;
        }
        #pragma unroll
        for (int off = 1; off < 32; off <<= 1) tsum += __shfl_xor(tsum, off, 32);
        int refl = 0;
        if (lane == 0) {
            const float lg = tsum + b3s;
            const float sc = 1.0f / (1.0f + expf(-lg));
            out[e] = sc;
            out[NE + (size_t)e] = (sc >= 0.5f) ? 1.0f : 0.0f;
            refl = (fabsf(lg) < EPS2) ? 1 : 0;
        }
        refl = __shfl(refl, 0, 64);
        asm volatile("s_waitcnt lgkmcnt(0)" ::: "memory");

        if (refl) {
            const float* sp = nf + (size_t)si * D_NODE;
            const float* tp = nf + (size_t)ti * D_NODE;
            const float* ep = ef + (size_t)e * D_EDGE;
            if (lane < 16)      ((float4*)&rows[wave][0])[lane]        = ((const float4*)sp)[lane];
            else if (lane < 32) ((float4*)&rows[wave][64])[lane - 16]  = ((const float4*)tp)[lane - 16];
            else if (lane < 40) ((float4*)&rows[wave][128])[lane - 32] = ((const float4*)ep)[lane - 32];
            asm volatile("s_waitcnt lgkmcnt(0)" ::: "memory");

            const float* rw = rows[wave];
            double a0 = (double)b1[lane], a1 = 0.0, a2 = 0.0, a3 = 0.0;
            const float* w1r = W1 + (size_t)lane * D_IN;
            #pragma unroll 4
            for (int k = 0; k < 160; k += 4) {
                a0 = fma((double)rw[k+0], (double)w1r[k+0], a0);
                a1 = fma((double)rw[k+1], (double)w1r[k+1], a1);
                a2 = fma((double)rw[k+2], (double)w1r[k+2], a2);
                a3 = fma((double)rw[k+3], (double)w1r[k+3], a3);
            }
            dfh[wave][lane] = fmax((a0 + a1) + (a2 + a3), 0.0);
            asm volatile("s_waitcnt lgkmcnt(0)" ::: "memory");

            double dsum = 0.0;
            if (lane < H2C) {
                double h0 = (double)b2[lane], h1 = 0.0, h2 = 0.0, h3 = 0.0;
                const float* w2r = W2 + (size_t)lane * HID;
                #pragma unroll 4
                for (int jj = 0; jj < 64; jj += 4) {
                    h0 = fma(dfh[wave][jj+0], (double)w2r[jj+0], h0);
                    h1 = fma(dfh[wave][jj+1], (double)w2r[jj+1], h1);
                    h2 = fma(dfh[wave][jj+2], (double)w2r[jj+2], h2);
                    h3 = fma(dfh[wave][jj+3], (double)w2r[jj+3], h3);
                }
                dsum = fmax((h0 + h1) + (h2 + h3), 0.0) * (double)W3[lane];
            }
            #pragma unroll
            for (int off = 1; off < 32; off <<= 1) dsum += __shfl_xor(dsum, off, 32);
            if (lane == 0) {
                const double logit = dsum + (double)b3[0];
                const float sc = (float)(1.0 / (1.0 + exp(-logit)));
                out[e] = sc;
                out[NE + (size_t)e] = (sc >= 0.5f) ? 1.0f : 0.0f;
            }
            asm volatile("s_waitcnt lgkmcnt(0)" ::: "memory");
        }
    }
}

// ---------- Fallback (tiny ws): proven f32 VALU path + atomic list ----------
__global__ void zero_counter_kernel(int* __restrict__ c) {
    if (blockIdx.x == 0 && threadIdx.x == 0) c[0] = 0;
}

__global__ __launch_bounds__(256, 4) void edge_mlp_f32_kernel(
    const float* __restrict__ nf, const int* __restrict__ ei,
    const float* __restrict__ ef,
    const float* __restrict__ W1, const float* __restrict__ b1,
    const float* __restrict__ W2, const float* __restrict__ b2,
    const float* __restrict__ W3, const float* __restrict__ b3,
    int* __restrict__ counter, int* __restrict__ list, int cap,
    float* __restrict__ out)
{
    const int e = blockIdx.x * blockDim.x + threadIdx.x;
    if (e >= NE) return;
    const int is64 = (ei[1]==0)&(ei[3]==0)&(ei[5]==0)&(ei[7]==0);
    int si, ti;
    if (is64) { si = ei[2*(size_t)e]; ti = ei[2*((size_t)NE + e)]; }
    else      { si = ei[e];           ti = ei[NE + e]; }
    const float* srcp = nf + (size_t)si * D_NODE;
    const float* tgtp = nf + (size_t)ti * D_NODE;
    const float* efp  = ef + (size_t)e  * D_EDGE;

    float acc[HID];
    #pragma unroll
    for (int j = 0; j < HID; ++j) acc[j] = b1[j];
    #pragma unroll 1
    for (int kc = 0; kc < D_IN / 16; ++kc) {
        const float* base = (kc < 4) ? (srcp + kc * 16)
                          : (kc < 8) ? (tgtp + (kc - 4) * 16)
                                     : (efp  + (kc - 8) * 16);
        float c[16];
        #pragma unroll
        for (int q = 0; q < 4; ++q) {
            const float4 v = *reinterpret_cast<const float4*>(base + q * 4);
            c[q*4+0]=v.x; c[q*4+1]=v.y; c[q*4+2]=v.z; c[q*4+3]=v.w;
        }
        #pragma unroll
        for (int j = 0; j < HID; ++j)
            #pragma unroll
            for (int q = 0; q < 16; ++q)
                acc[j] = fmaf(c[q], W1[j*D_IN + kc*16 + q], acc[j]);
    }
    #pragma unroll
    for (int j = 0; j < HID; ++j) acc[j] = fmaxf(acc[j], 0.0f);

    float logit = b3[0];
    #pragma unroll 1
    for (int jj = 0; jj < H2C; ++jj) {
        float h = b2[jj];
        #pragma unroll
        for (int j = 0; j < HID; ++j) h = fmaf(acc[j], W2[jj*HID + j], h);
        logit = fmaf(fmaxf(h, 0.0f), W3[jj], logit);
    }
    const float score = 1.0f / (1.0f + expf(-logit));
    out[e] = score;
    out[(size_t)NE + e] = (score >= 0.5f) ? 1.0f : 0.0f;
    if (fabsf(logit) < EPS2) {
        const int idx = atomicAdd(counter, 1);
        if (idx < cap) list[idx] = e;
    }
}

__global__ __launch_bounds__(256) void fixup_list_f64_kernel(
    const float* __restrict__ nf, const int* __restrict__ ei,
    const float* __restrict__ ef,
    const float* __restrict__ W1, const float* __restrict__ b1,
    const float* __restrict__ W2, const float* __restrict__ b2,
    const float* __restrict__ W3, const float* __restrict__ b3,
    const int* __restrict__ counter, const int* __restrict__ list, int cap,
    float* __restrict__ out)
{
    __shared__ double fh[4][HID];
    __shared__ __attribute__((aligned(16))) float rows[4][160];
    const int wave = threadIdx.x >> 6, lane = threadIdx.x & 63;
    const int nwaves = (gridDim.x * blockDim.x) >> 6;
    const int wid = (blockIdx.x * blockDim.x + threadIdx.x) >> 6;
    int n = counter[0]; if (n > cap) n = cap;
    const int is64 = (ei[1]==0)&(ei[3]==0)&(ei[5]==0)&(ei[7]==0);

    for (int i = wid; i < n; i += nwaves) {
        const int e = list[i];
        int si, ti;
        if (is64) { si = ei[(size_t)2*e]; ti = ei[(size_t)2*(NE + (long long)e)]; }
        else      { si = ei[e];           ti = ei[NE + (size_t)e]; }
        const float* sp = nf + (size_t)si * D_NODE;
        const float* tp = nf + (size_t)ti * D_NODE;
        const float* ep = ef + (size_t)e * D_EDGE;

        if (lane < 16)      ((float4*)&rows[wave][0])[lane]        = ((const float4*)sp)[lane];
        else if (lane < 32) ((float4*)&rows[wave][64])[lane - 16]  = ((const float4*)tp)[lane - 16];
        else if (lane < 40) ((float4*)&rows[wave][128])[lane - 32] = ((const float4*)ep)[lane - 32];
        asm volatile("s_waitcnt lgkmcnt(0)" ::: "memory");

        const float* rw = rows[wave];
        double a0 = (double)b1[lane], a1 = 0.0, a2 = 0.0, a3 = 0.0;
        const float* w1r = W1 + (size_t)lane * D_IN;
        #pragma unroll 4
        for (int k = 0; k < 160; k += 4) {
            a0 = fma((double)rw[k+0], (double)w1r[k+0], a0);
            a1 = fma((double)rw[k+1], (double)w1r[k+1], a1);
            a2 = fma((double)rw[k+2], (double)w1r[k+2], a2);
            a3 = fma((double)rw[k+3], (double)w1r[k+3], a3);
        }
        fh[wave][lane] = fmax((a0 + a1) + (a2 + a3), 0.0);
        asm volatile("s_waitcnt lgkmcnt(0)" ::: "memory");

        double tsum = 0.0;
        if (lane < H2C) {
            double h0 = (double)b2[lane], h1 = 0.0, h2 = 0.0, h3 = 0.0;
            const float* w2r = W2 + (size_t)lane * HID;
            #pragma unroll 4
            for (int jj = 0; jj < 64; jj += 4) {
                h0 = fma(fh[wave][jj+0], (double)w2r[jj+0], h0);
                h1 = fma(fh[wave][jj+1], (double)w2r[jj+1], h1);
                h2 = fma(fh[wave][jj+2], (double)w2r[jj+2], h2);
                h3 = fma(fh[wave][jj+3], (double)w2r[jj+3], h3);
            }
            tsum = fmax((h0 + h1) + (h2 + h3), 0.0) * (double)W3[lane];
        }
        #pragma unroll
        for (int off = 1; off < 32; off <<= 1) tsum += __shfl_xor(tsum, off, 32);
        if (lane == 0) {
            const double logit = tsum + (double)b3[0];
            const float sc = (float)(1.0 / (1.0 + exp(-logit)));
            out[e] = sc;
            out[NE + (size_t)e] = (sc >= 0.5f) ? 1.0f : 0.0f;
        }
        asm volatile("s_waitcnt lgkmcnt(0)" ::: "memory");
    }
}

extern "C" void kernel_launch(void* const* d_in, const int* in_sizes, int n_in,
                              void* d_out, int out_size, void* d_ws, size_t ws_size,
                              hipStream_t stream) {
    const float* nf = (const float*)d_in[0];
    const int*   ei = (const int*)  d_in[1];
    const float* ef = (const float*)d_in[2];
    const float* W1 = (const float*)d_in[3];
    const float* b1 = (const float*)d_in[4];
    const float* W2 = (const float*)d_in[5];
    const float* b2 = (const float*)d_in[6];
    const float* W3 = (const float*)d_in[7];
    const float* b3 = (const float*)d_in[8];
    float* out = (float*)d_out;
    unsigned char* ws = (unsigned char*)d_ws;

    if (ws_size >= (size_t)WS_V17_MIN) {
        unsigned short* Uhi = (unsigned short*)(ws + WS_UHI);
        unsigned short* Ulo = (unsigned short*)(ws + WS_ULO);
        unsigned short* Vhi = (unsigned short*)(ws + WS_VHI);
        unsigned short* Vlo = (unsigned short*)(ws + WS_VLO);
        unsigned short* mask1 = (unsigned short*)(ws + WS_MASK);
        int* counter = (int*)ws;
        int* list = (int*)(ws + WS_LIST);
        hipLaunchKernelGGL(prep_pack_v15, dim3(6), dim3(256), 0, stream, W1, W2, ws);
        hipLaunchKernelGGL(prep_uv_v15, dim3((N_NODES/16 + 3) / 4), dim3(256), 0, stream,
                           nf, b1,
                           (const unsigned short*)(ws + WS_AS_OFF),
                           (const unsigned short*)(ws + WS_AT_OFF),
                           Uhi, Ulo, Vhi, Vlo);
        hipLaunchKernelGGL(edge_mlp_v8_kernel, dim3((NE + 127) / 128), dim3(256), 0, stream,
                           ei, ef, b2, W3, b3,
                           (const unsigned short*)(ws + WS_A1_OFF),
                           (const unsigned short*)(ws + WS_A2_OFF),
                           Uhi, Vhi, mask1, out);
        hipLaunchKernelGGL(compact_v17, dim3(256), dim3(256), 0, stream,
                           mask1, counter, list);
        hipLaunchKernelGGL(fixup_list_v17, dim3(2048), dim3(256), 0, stream,
                           nf, ei, ef, W1, b1, W2, b2, W3, b3,
                           Uhi, Ulo, Vhi, Vlo, counter, list, out);
    } else {
        int* counter = (int*)ws;
        long long cap_ll = ((long long)ws_size - 16) / 4;
        const int cap = (int)(cap_ll < 0 ? 0 : (cap_ll > NE ? NE : cap_ll));
        int* slist = (int*)(ws + 16);
        hipLaunchKernelGGL(zero_counter_kernel, dim3(1), dim3(64), 0, stream, counter);
        hipLaunchKernelGGL(edge_mlp_f32_kernel, dim3((NE + 255)/256), dim3(256), 0, stream,
                           nf, ei, ef, W1, b1, W2, b2, W3, b3, counter, slist, cap, out);
        hipLaunchKernelGGL(fixup_list_f64_kernel, dim3(512), dim3(256), 0, stream,
                           nf, ei, ef, W1, b1, W2, b2, W3, b3, counter, slist, cap, out);
    }
}